// Round 4
// baseline (1514.157 us; speedup 1.0000x reference)
//
#include <hip/hip_runtime.h>
#include <math.h>

typedef __attribute__((ext_vector_type(8))) short short8;
typedef __attribute__((ext_vector_type(4))) float f32x4;

// ---------------- helpers ----------------
__device__ __forceinline__ float wred_sum(float v) {
#pragma unroll
  for (int off = 32; off; off >>= 1) v += __shfl_xor(v, off, 64);
  return v;
}
__device__ __forceinline__ float wred_max(float v) {
#pragma unroll
  for (int off = 32; off; off >>= 1) v = fmaxf(v, __shfl_xor(v, off, 64));
  return v;
}
__device__ __forceinline__ unsigned f2key(float x) {
  unsigned b = __float_as_uint(x);
  return (b & 0x80000000u) ? ~b : (b | 0x80000000u);
}
__device__ __forceinline__ float key2f(unsigned k) {
  unsigned b = (k & 0x80000000u) ? (k & 0x7FFFFFFFu) : ~k;
  return __uint_as_float(b);
}
// bf16 <-> f32
__device__ __forceinline__ float b2f(unsigned short u) {
  return __uint_as_float(((unsigned)u) << 16);
}
__device__ __forceinline__ unsigned short f2b(float f) {
  unsigned b = __float_as_uint(f);
  return (unsigned short)((b + 0x7FFFu + ((b >> 16) & 1u)) >> 16);
}

// ---------------- f32 -> bf16 cast (5 segments, one launch) ----------------
__global__ __launch_bounds__(256) void k_cast5(
    const float* __restrict__ s0, ushort* __restrict__ d0, int n0,
    const float* __restrict__ s1, ushort* __restrict__ d1, int n1,
    const float* __restrict__ s2, ushort* __restrict__ d2, int n2,
    const float* __restrict__ s3, ushort* __restrict__ d3, int n3,
    const float* __restrict__ s4, ushort* __restrict__ d4, int n4) {
  int t = (blockIdx.x * 256 + threadIdx.x) * 4;
  const float* s; ushort* d; int off = t;
  if (off < n0) { s = s0; d = d0; }
  else { off -= n0;
    if (off < n1) { s = s1; d = d1; }
    else { off -= n1;
      if (off < n2) { s = s2; d = d2; }
      else { off -= n2;
        if (off < n3) { s = s3; d = d3; }
        else { off -= n3;
          if (off < n4) { s = s4; d = d4; }
          else return; } } } }
  float4 v = *(const float4*)(s + off);
  ushort4 o;
  o.x = f2b(v.x); o.y = f2b(v.y); o.z = f2b(v.z); o.w = f2b(v.w);
  *(ushort4*)(d + off) = o;
}

// ---------------- self-loop mean edge_attr + degree count ----------------
__global__ __launch_bounds__(256) void k_count_ea(const int* __restrict__ dst,
    const float* __restrict__ ea, int* __restrict__ cnt_i,
    float* __restrict__ sum_ea, int E) {
  int e = blockIdx.x * 256 + threadIdx.x;
  if (e >= E) return;
  int d = dst[e];
  atomicAdd(&cnt_i[d], 1);
  atomicAdd(&sum_ea[d], ea[e]);
}

__global__ __launch_bounds__(256) void k_mean(const int* __restrict__ cnt_i,
    const float* __restrict__ sum_ea, float* __restrict__ mean_ea, int N) {
  int n = blockIdx.x * 256 + threadIdx.x;
  if (n >= N) return;
  mean_ea[n] = sum_ea[n] / fmaxf((float)cnt_i[n], 1.0f);
}

// exclusive scan of (cnt+1) over N nodes -> row_start[N+1], cursor copy
__global__ __launch_bounds__(1024) void k_scan(const int* __restrict__ cnt_i,
    int* __restrict__ row_st, int* __restrict__ cursor, int N) {
  __shared__ int sums[1024];
  int tid = threadIdx.x;
  int per = (N + 1023) / 1024;
  int begin = tid * per, end = min(begin + per, N);
  int s = 0;
  for (int i = begin; i < end; ++i) s += cnt_i[i] + 1;
  sums[tid] = s;
  __syncthreads();
  for (int off = 1; off < 1024; off <<= 1) {
    int v = (tid >= off) ? sums[tid - off] : 0;
    __syncthreads();
    sums[tid] += v;
    __syncthreads();
  }
  int prefix = (tid == 0) ? 0 : sums[tid - 1];
  for (int i = begin; i < end; ++i) {
    row_st[i] = prefix;
    cursor[i] = prefix;
    prefix += cnt_i[i] + 1;
  }
  if (tid == 0) row_st[N] = sums[1023];
}

// scatter: store source-node id and edge value directly (no perm indirection)
__global__ __launch_bounds__(256) void k_scatter(const int* __restrict__ dst,
    const int* __restrict__ src, const float* __restrict__ ea,
    const float* __restrict__ mean_ea, int* __restrict__ cursor,
    int* __restrict__ srcp, float* __restrict__ eap, int E, int E2) {
  int e = blockIdx.x * 256 + threadIdx.x;
  if (e >= E2) return;
  int d, sn; float av;
  if (e < E) { d = dst[e]; sn = src[e]; av = ea[e]; }
  else { d = e - E; sn = d; av = mean_ea[d]; }
  int pos = atomicAdd(&cursor[d], 1);
  srcp[pos] = sn;
  eap[pos] = av;
}

// ---------------- bf16 MFMA GEMM: C[M,Nc](bf16) = A[M,K](bf16) * W[Nc,K](bf16)^T + bias(f32)
// gridDim.z selects (W0,b0,C0) or (W1,b1,C1); 4 waves; tile 64 rows x 64 cols
__global__ __launch_bounds__(256) void k_gemm_mfma2(const ushort* __restrict__ A,
    const ushort* __restrict__ W0, const float* __restrict__ b0, ushort* __restrict__ C0,
    const ushort* __restrict__ W1, const float* __restrict__ b1, ushort* __restrict__ C1,
    int M, int Nc, int K) {
  const ushort* W = blockIdx.z ? W1 : W0;
  const float* bias = blockIdx.z ? b1 : b0;
  ushort* C = blockIdx.z ? C1 : C0;
  int wave = threadIdx.x >> 6, lane = threadIdx.x & 63;
  int m0 = blockIdx.x * 64 + wave * 16;
  int n0 = blockIdx.y * 64;
  int r = lane & 15, g = lane >> 4;
  f32x4 acc[4] = {};
  int am = min(m0 + r, M - 1);
  const ushort* Arow = A + (size_t)am * K + g * 8;
  const ushort* Wrow = W + (size_t)(n0 + r) * K + g * 8;
  for (int k0 = 0; k0 < K; k0 += 32) {
    short8 a = *(const short8*)(const void*)(Arow + k0);
#pragma unroll
    for (int c = 0; c < 4; ++c) {
      short8 b = *(const short8*)(const void*)(Wrow + (size_t)c * 16 * K + k0);
      acc[c] = __builtin_amdgcn_mfma_f32_16x16x32_bf16(a, b, acc[c], 0, 0, 0);
    }
  }
#pragma unroll
  for (int c = 0; c < 4; ++c) {
    int gn = n0 + c * 16 + r;
    float bv = bias[gn];
#pragma unroll
    for (int j = 0; j < 4; ++j) {
      int gm = m0 + g * 4 + j;
      if (gm < M) C[(size_t)gm * Nc + gn] = f2b(acc[c][j] + bv);
    }
  }
}

// ---------------- layer 1 fused: scores + online softmax + aggregation ----------------
__global__ __launch_bounds__(256) void k_fused1(const ushort* __restrict__ xl,
    const ushort* __restrict__ xr, const int* __restrict__ srcp,
    const float* __restrict__ eap, const int* __restrict__ row_st,
    const float* __restrict__ We, const float* __restrict__ att,
    const float* __restrict__ bias, ushort* __restrict__ out, int N) {
  int n = blockIdx.x * 4 + (threadIdx.x >> 6);
  int lane = threadIdx.x & 63;
  if (n >= N) return;
  const float4 We4 = ((const float4*)We)[lane];
  const float4 at4 = ((const float4*)att)[lane];
  ushort4 xru = *(const ushort4*)(xr + (size_t)n * 256 + lane * 4);
  float xrx = b2f(xru.x), xry = b2f(xru.y), xrz = b2f(xru.z), xrw = b2f(xru.w);
  int a = row_st[n], b = row_st[n + 1];
  float m = -INFINITY, den = 0.f;
  float ax = 0.f, ay = 0.f, az = 0.f, aw = 0.f;
  int sn_nx = srcp[a];
  float av_nx = eap[a];
  for (int i = a; i < b; ++i) {
    int sn = sn_nx;
    float av = av_nx;
    ushort4 xu = *(const ushort4*)(xl + (size_t)sn * 256 + lane * 4);
    if (i + 1 < b) { sn_nx = srcp[i + 1]; av_nx = eap[i + 1]; }
    float x0 = b2f(xu.x), x1 = b2f(xu.y), x2 = b2f(xu.z), x3 = b2f(xu.w);
    float vx = x0 + xrx + av * We4.x; vx = vx > 0.f ? vx : 0.2f * vx;
    float vy = x1 + xry + av * We4.y; vy = vy > 0.f ? vy : 0.2f * vy;
    float vz = x2 + xrz + av * We4.z; vz = vz > 0.f ? vz : 0.2f * vz;
    float vw = x3 + xrw + av * We4.w; vw = vw > 0.f ? vw : 0.2f * vw;
    float t = at4.x * vx + at4.y * vy + at4.z * vz + at4.w * vw;
    t += __shfl_xor(t, 1, 16);
    t += __shfl_xor(t, 2, 16);
    t += __shfl_xor(t, 4, 16);
    t += __shfl_xor(t, 8, 16);
    if (t > m) {
      float sc = __expf(m - t);
      m = t;
      den *= sc; ax *= sc; ay *= sc; az *= sc; aw *= sc;
    }
    float ex = __expf(t - m);
    den += ex;
    ax += ex * x0; ay += ex * x1; az += ex * x2; aw += ex * x3;
  }
  float inv = 1.f / (den + 1e-16f);
  const float4 b4 = ((const float4*)bias)[lane];
  ushort4 o;
  o.x = f2b(fmaxf(ax * inv + b4.x, 0.f));
  o.y = f2b(fmaxf(ay * inv + b4.y, 0.f));
  o.z = f2b(fmaxf(az * inv + b4.z, 0.f));
  o.w = f2b(fmaxf(aw * inv + b4.w, 0.f));
  *(ushort4*)(out + (size_t)n * 256 + lane * 4) = o;
}

// ---------------- layer 2 fused (H=1, C=64) ----------------
__global__ __launch_bounds__(256) void k_fused2(const ushort* __restrict__ xl,
    const ushort* __restrict__ xr, const int* __restrict__ srcp,
    const float* __restrict__ eap, const int* __restrict__ row_st,
    const float* __restrict__ We, const float* __restrict__ att,
    const float* __restrict__ bias, float* __restrict__ out, int N) {
  int n = blockIdx.x * 4 + (threadIdx.x >> 6);
  int lane = threadIdx.x & 63;
  if (n >= N) return;
  const float Wev = We[lane];
  const float atv = att[lane];
  const float xrv = b2f(xr[(size_t)n * 64 + lane]);
  int a = row_st[n], b = row_st[n + 1];
  float m = -INFINITY, den = 0.f, acc = 0.f;
  int sn_nx = srcp[a];
  float av_nx = eap[a];
  for (int i = a; i < b; ++i) {
    int sn = sn_nx;
    float av = av_nx;
    float xv = b2f(xl[(size_t)sn * 64 + lane]);
    if (i + 1 < b) { sn_nx = srcp[i + 1]; av_nx = eap[i + 1]; }
    float v = xv + xrv + av * Wev;
    v = v > 0.f ? v : 0.2f * v;
    float t = wred_sum(atv * v);
    if (t > m) {
      float sc = __expf(m - t);
      m = t; den *= sc; acc *= sc;
    }
    float ex = __expf(t - m);
    den += ex;
    acc += ex * xv;
  }
  float v = acc / (den + 1e-16f) + bias[lane];
  out[(size_t)n * 64 + lane] = v > 0.f ? v : 0.f;
}

// ---------------- global mean pool ----------------
__global__ __launch_bounds__(256) void k_pool(const float* __restrict__ h2,
    float* __restrict__ g_sum, int N) {
  __shared__ float red[4][64];
  int b = blockIdx.x, tid = threadIdx.x;
  int lane = tid & 63, w = tid >> 6;
  int rows_per = (N + gridDim.x - 1) / gridDim.x;
  int r0 = b * rows_per, r1 = min(r0 + rows_per, N);
  float s = 0;
  for (int r = r0 + w; r < r1; r += 4) s += h2[(size_t)r * 64 + lane];
  red[w][lane] = s;
  __syncthreads();
  if (w == 0) {
    float v = red[0][lane] + red[1][lane] + red[2][lane] + red[3][lane];
    atomicAdd(&g_sum[lane], v);
  }
}

// mean -> g, state potential, sigmoid(alpha)
__global__ void k_head(const float* __restrict__ g_sum, const float* __restrict__ Wp,
    const float* __restrict__ bp, const float* __restrict__ alpha,
    float* __restrict__ g, float* __restrict__ out, int N, int NA) {
  int lane = threadIdx.x;
  float gv = g_sum[lane] / (float)N;
  g[lane] = gv;
  float t = wred_sum(gv * Wp[lane]);
  if (lane == 0) {
    float sp = t + bp[0];
    out[NA] = sp > 0.f ? sp : 0.f;
    out[NA + 1] = 1.f / (1.f + __expf(-alpha[0]));
  }
}

__global__ void k_aflag(const int* __restrict__ actions, unsigned char* __restrict__ aflag,
                        int n_act) {
  int i = threadIdx.x;
  if (i < n_act) aflag[actions[i]] = 1;
}

// ---------------- masked logits: coalesced GEMV (16 lanes per row) ----------------
__global__ __launch_bounds__(256) void k_logits(const float* __restrict__ g,
    const float* __restrict__ Wf, const float* __restrict__ bf,
    const unsigned char* __restrict__ aflag, const int* __restrict__ src,
    const int* __restrict__ dst, float* __restrict__ logits,
    unsigned* __restrict__ gmax_key, int E, int NA) {
  __shared__ float gs[64];
  int tid = threadIdx.x;
  if (tid < 64) gs[tid] = g[tid];
  __syncthreads();
  int l16 = tid & 15;
  int row = blockIdx.x * 16 + (tid >> 4);
  float val = -INFINITY;
  if (row < NA) {
    bool keep = (!aflag[row]) && (row >= E || src[row] != dst[row]);
    if (keep) {
      float4 gv = ((const float4*)gs)[l16];
      float4 w = *(const float4*)(Wf + (size_t)row * 64 + l16 * 4);
      float acc = w.x * gv.x + w.y * gv.y + w.z * gv.z + w.w * gv.w;
      acc += __shfl_xor(acc, 1, 16);
      acc += __shfl_xor(acc, 2, 16);
      acc += __shfl_xor(acc, 4, 16);
      acc += __shfl_xor(acc, 8, 16);
      val = acc + bf[row];
    }
    if (l16 == 0) logits[row] = val;
  }
  float mv = wred_max(val);
  if ((tid & 63) == 0) atomicMax(gmax_key, f2key(mv));
}

__global__ __launch_bounds__(256) void k_exp(float* __restrict__ logits,
    const unsigned* __restrict__ gmax_key, float* __restrict__ gsum, int NA) {
  int i = blockIdx.x * 256 + threadIdx.x;
  float gmax = key2f(*gmax_key);
  float ex = 0.f;
  if (i < NA) {
    float v = logits[i];
    ex = (v == -INFINITY) ? 0.f : __expf(v - gmax);
    logits[i] = ex;
  }
  float s = wred_sum(ex);
  if ((threadIdx.x & 63) == 0) atomicAdd(gsum, s);
}

__global__ __launch_bounds__(256) void k_norm(const float* __restrict__ logits,
    const float* __restrict__ gsum, float* __restrict__ out, int NA) {
  int i = blockIdx.x * 256 + threadIdx.x;
  if (i < NA) out[i] = logits[i] / (*gsum);
}

// ---------------- launch ----------------
extern "C" void kernel_launch(void* const* d_in, const int* in_sizes, int n_in,
                              void* d_out, int out_size, void* d_ws, size_t ws_size,
                              hipStream_t stream) {
  const float* x      = (const float*)d_in[0];
  const int*   eidx   = (const int*)d_in[1];
  const float* eattr  = (const float*)d_in[2];
  const int*   actions= (const int*)d_in[3];
  const float* Wl1 = (const float*)d_in[4];
  const float* bl1 = (const float*)d_in[5];
  const float* Wr1 = (const float*)d_in[6];
  const float* br1 = (const float*)d_in[7];
  const float* We1 = (const float*)d_in[8];
  const float* att1= (const float*)d_in[9];
  const float* bias1=(const float*)d_in[10];
  const float* Wl2 = (const float*)d_in[11];
  const float* bl2 = (const float*)d_in[12];
  const float* Wr2 = (const float*)d_in[13];
  const float* br2 = (const float*)d_in[14];
  const float* We2 = (const float*)d_in[15];
  const float* att2= (const float*)d_in[16];
  const float* bias2=(const float*)d_in[17];
  const float* Wf  = (const float*)d_in[18];
  const float* bf  = (const float*)d_in[19];
  const float* Wp  = (const float*)d_in[20];
  const float* bp  = (const float*)d_in[21];
  const float* alpha=(const float*)d_in[22];

  const int F = 128;
  const int N = in_sizes[0] / F;       // 20000
  const int E = in_sizes[2];           // 400000
  const int E2 = E + N;
  const int NA = E + 1;
  const int n_act = in_sizes[3];
  const int* src = eidx;
  const int* dst = eidx + E;
  const int hid = 64;

  float* ws = (float*)d_ws;
  size_t p = 0;
  int*      cnt_i    = (int*)(ws + p);      p += (size_t)N;
  float*    sum_ea   = ws + p;              p += (size_t)N;
  float*    g_sum    = ws + p;              p += 64;
  unsigned* gmax_key = (unsigned*)(ws + p); p += 64;
  float*    gsum     = ws + p;              p += 64;
  size_t zero_bytes = p * sizeof(float);
  float*    g        = ws + p;              p += 64;
  float*    mean_ea  = ws + p;              p += (size_t)N;
  int*      row_st   = (int*)(ws + p);      p += (size_t)N + 64;
  int*      cursor   = (int*)(ws + p);      p += (size_t)N;
  int*      srcp     = (int*)(ws + p);      p += (size_t)E2;
  float*    eap      = ws + p;              p += (size_t)E2;
  float*    logits   = ws + p;              p += (size_t)NA + 64;
  p = (p + 3) & ~(size_t)3;                 // 16B align for bf16 region
  float*    h2       = ws + p;              p += (size_t)N * hid;
  ushort* ub = (ushort*)(ws + p);
  size_t q = 0;
  ushort* xb   = ub + q; q += (size_t)N * F;        // x bf16
  ushort* wl1b = ub + q; q += (size_t)256 * 128;
  ushort* wr1b = ub + q; q += (size_t)256 * 128;
  ushort* wl2b = ub + q; q += (size_t)64 * 256;
  ushort* wr2b = ub + q; q += (size_t)64 * 256;
  ushort* xl1b = ub + q; q += (size_t)N * 256;
  ushort* xr1b = ub + q; q += (size_t)N * 256;
  ushort* h1b  = ub + q; q += (size_t)N * 256;
  ushort* xl2b = ub + q; q += (size_t)N * 64;
  ushort* xr2b = ub + q; q += (size_t)N * 64;
  unsigned char* aflag = (unsigned char*)(ub + q);

  float* out = (float*)d_out;

  hipMemsetAsync(d_ws, 0, zero_bytes, stream);
  hipMemsetAsync(aflag, 0, (size_t)NA, stream);

  // casts: x + 4 weight matrices -> bf16
  {
    int n0 = N * F, n1 = 256 * 128, n2 = 256 * 128, n3 = 64 * 256, n4 = 64 * 256;
    int tot4 = (n0 + n1 + n2 + n3 + n4) / 4;
    k_cast5<<<(tot4 + 255) / 256, 256, 0, stream>>>(
        x, xb, n0, Wl1, wl1b, n1, Wr1, wr1b, n2, Wl2, wl2b, n3, Wr2, wr2b, n4);
  }

  // CSR build + self-loop edge attr
  k_count_ea<<<(E + 255) / 256, 256, 0, stream>>>(dst, eattr, cnt_i, sum_ea, E);
  k_mean<<<(N + 255) / 256, 256, 0, stream>>>(cnt_i, sum_ea, mean_ea, N);
  k_scan<<<1, 1024, 0, stream>>>(cnt_i, row_st, cursor, N);
  k_scatter<<<(E2 + 255) / 256, 256, 0, stream>>>(dst, src, eattr, mean_ea,
                                                  cursor, srcp, eap, E, E2);

  // layer 1 projections (bf16 MFMA): xl1b, xr1b in one launch
  {
    dim3 g1((N + 63) / 64, 256 / 64, 2);
    k_gemm_mfma2<<<g1, 256, 0, stream>>>(xb, wl1b, bl1, xl1b, wr1b, br1, xr1b,
                                         N, 256, 128);
  }
  k_fused1<<<(N + 3) / 4, 256, 0, stream>>>(xl1b, xr1b, srcp, eap, row_st,
                                            We1, att1, bias1, h1b, N);

  // layer 2 projections from h1b: xl2b, xr2b in one launch
  {
    dim3 g2((N + 63) / 64, 1, 2);
    k_gemm_mfma2<<<g2, 256, 0, stream>>>(h1b, wl2b, bl2, xl2b, wr2b, br2, xr2b,
                                         N, 64, 256);
  }
  k_fused2<<<(N + 3) / 4, 256, 0, stream>>>(xl2b, xr2b, srcp, eap, row_st,
                                            We2, att2, bias2, h2, N);

  // head
  k_pool<<<128, 256, 0, stream>>>(h2, g_sum, N);
  k_head<<<1, 64, 0, stream>>>(g_sum, Wp, bp, alpha, g, out, N, NA);
  k_aflag<<<1, 128, 0, stream>>>(actions, aflag, n_act);
  k_logits<<<(NA + 15) / 16, 256, 0, stream>>>(g, Wf, bf, aflag, src, dst,
                                               logits, gmax_key, E, NA);
  int nb = (NA + 255) / 256;
  k_exp<<<nb, 256, 0, stream>>>(logits, gmax_key, gsum, NA);
  k_norm<<<nb, 256, 0, stream>>>(logits, gsum, out, NA);
}

// Round 5
// 336.257 us; speedup vs baseline: 4.5030x; 4.5030x over previous
//
#include <hip/hip_runtime.h>
#include <math.h>

typedef __attribute__((ext_vector_type(8))) short short8;
typedef __attribute__((ext_vector_type(4))) float f32x4;

// ---------------- helpers ----------------
__device__ __forceinline__ float wred_sum(float v) {
#pragma unroll
  for (int off = 32; off; off >>= 1) v += __shfl_xor(v, off, 64);
  return v;
}
__device__ __forceinline__ float wred_max(float v) {
#pragma unroll
  for (int off = 32; off; off >>= 1) v = fmaxf(v, __shfl_xor(v, off, 64));
  return v;
}
__device__ __forceinline__ unsigned f2key(float x) {
  unsigned b = __float_as_uint(x);
  return (b & 0x80000000u) ? ~b : (b | 0x80000000u);
}
__device__ __forceinline__ float key2f(unsigned k) {
  unsigned b = (k & 0x80000000u) ? (k & 0x7FFFFFFFu) : ~k;
  return __uint_as_float(b);
}
// bf16 <-> f32
__device__ __forceinline__ float b2f(unsigned short u) {
  return __uint_as_float(((unsigned)u) << 16);
}
__device__ __forceinline__ unsigned short f2b(float f) {
  unsigned b = __float_as_uint(f);
  return (unsigned short)((b + 0x7FFFu + ((b >> 16) & 1u)) >> 16);
}

// ---------------- f32 -> bf16 cast (5 segments, one launch) ----------------
__global__ __launch_bounds__(256) void k_cast5(
    const float* __restrict__ s0, ushort* __restrict__ d0, int n0,
    const float* __restrict__ s1, ushort* __restrict__ d1, int n1,
    const float* __restrict__ s2, ushort* __restrict__ d2, int n2,
    const float* __restrict__ s3, ushort* __restrict__ d3, int n3,
    const float* __restrict__ s4, ushort* __restrict__ d4, int n4) {
  int t = (blockIdx.x * 256 + threadIdx.x) * 4;
  const float* s; ushort* d; int off = t;
  if (off < n0) { s = s0; d = d0; }
  else { off -= n0;
    if (off < n1) { s = s1; d = d1; }
    else { off -= n1;
      if (off < n2) { s = s2; d = d2; }
      else { off -= n2;
        if (off < n3) { s = s3; d = d3; }
        else { off -= n3;
          if (off < n4) { s = s4; d = d4; }
          else return; } } } }
  float4 v = *(const float4*)(s + off);
  ushort4 o;
  o.x = f2b(v.x); o.y = f2b(v.y); o.z = f2b(v.z); o.w = f2b(v.w);
  *(ushort4*)(d + off) = o;
}

// ---------------- self-loop mean edge_attr + degree count ----------------
__global__ __launch_bounds__(256) void k_count_ea(const int* __restrict__ dst,
    const float* __restrict__ ea, int* __restrict__ cnt_i,
    float* __restrict__ sum_ea, int E) {
  int e = blockIdx.x * 256 + threadIdx.x;
  if (e >= E) return;
  int d = dst[e];
  atomicAdd(&cnt_i[d], 1);
  atomicAdd(&sum_ea[d], ea[e]);
}

__global__ __launch_bounds__(256) void k_mean(const int* __restrict__ cnt_i,
    const float* __restrict__ sum_ea, float* __restrict__ mean_ea, int N) {
  int n = blockIdx.x * 256 + threadIdx.x;
  if (n >= N) return;
  mean_ea[n] = sum_ea[n] / fmaxf((float)cnt_i[n], 1.0f);
}

// exclusive scan of (cnt+1) over N nodes -> row_start[N+1], cursor copy
__global__ __launch_bounds__(1024) void k_scan(const int* __restrict__ cnt_i,
    int* __restrict__ row_st, int* __restrict__ cursor, int N) {
  __shared__ int sums[1024];
  int tid = threadIdx.x;
  int per = (N + 1023) / 1024;
  int begin = tid * per, end = min(begin + per, N);
  int s = 0;
  for (int i = begin; i < end; ++i) s += cnt_i[i] + 1;
  sums[tid] = s;
  __syncthreads();
  for (int off = 1; off < 1024; off <<= 1) {
    int v = (tid >= off) ? sums[tid - off] : 0;
    __syncthreads();
    sums[tid] += v;
    __syncthreads();
  }
  int prefix = (tid == 0) ? 0 : sums[tid - 1];
  for (int i = begin; i < end; ++i) {
    row_st[i] = prefix;
    cursor[i] = prefix;
    prefix += cnt_i[i] + 1;
  }
  if (tid == 0) row_st[N] = sums[1023];
}

// scatter: store source-node id and edge value directly (no perm indirection)
__global__ __launch_bounds__(256) void k_scatter(const int* __restrict__ dst,
    const int* __restrict__ src, const float* __restrict__ ea,
    const float* __restrict__ mean_ea, int* __restrict__ cursor,
    int* __restrict__ srcp, float* __restrict__ eap, int E, int E2) {
  int e = blockIdx.x * 256 + threadIdx.x;
  if (e >= E2) return;
  int d, sn; float av;
  if (e < E) { d = dst[e]; sn = src[e]; av = ea[e]; }
  else { d = e - E; sn = d; av = mean_ea[d]; }
  int pos = atomicAdd(&cursor[d], 1);
  srcp[pos] = sn;
  eap[pos] = av;
}

// ---------------- bf16 MFMA GEMM: C[M,Nc](bf16) = A[M,K](bf16) * W[Nc,K](bf16)^T + bias(f32)
// gridDim.z selects (W0,b0,C0) or (W1,b1,C1); 4 waves; tile 64 rows x 64 cols
__global__ __launch_bounds__(256) void k_gemm_mfma2(const ushort* __restrict__ A,
    const ushort* __restrict__ W0, const float* __restrict__ b0, ushort* __restrict__ C0,
    const ushort* __restrict__ W1, const float* __restrict__ b1, ushort* __restrict__ C1,
    int M, int Nc, int K) {
  const ushort* W = blockIdx.z ? W1 : W0;
  const float* bias = blockIdx.z ? b1 : b0;
  ushort* C = blockIdx.z ? C1 : C0;
  int wave = threadIdx.x >> 6, lane = threadIdx.x & 63;
  int m0 = blockIdx.x * 64 + wave * 16;
  int n0 = blockIdx.y * 64;
  int r = lane & 15, g = lane >> 4;
  f32x4 acc[4] = {};
  int am = min(m0 + r, M - 1);
  const ushort* Arow = A + (size_t)am * K + g * 8;
  const ushort* Wrow = W + (size_t)(n0 + r) * K + g * 8;
  for (int k0 = 0; k0 < K; k0 += 32) {
    short8 a = *(const short8*)(const void*)(Arow + k0);
#pragma unroll
    for (int c = 0; c < 4; ++c) {
      short8 b = *(const short8*)(const void*)(Wrow + (size_t)c * 16 * K + k0);
      acc[c] = __builtin_amdgcn_mfma_f32_16x16x32_bf16(a, b, acc[c], 0, 0, 0);
    }
  }
#pragma unroll
  for (int c = 0; c < 4; ++c) {
    int gn = n0 + c * 16 + r;
    float bv = bias[gn];
#pragma unroll
    for (int j = 0; j < 4; ++j) {
      int gm = m0 + g * 4 + j;
      if (gm < M) C[(size_t)gm * Nc + gn] = f2b(acc[c][j] + bv);
    }
  }
}

// ---------------- layer 1 fused: scores + online softmax + aggregation ----------------
__global__ __launch_bounds__(256) void k_fused1(const ushort* __restrict__ xl,
    const ushort* __restrict__ xr, const int* __restrict__ srcp,
    const float* __restrict__ eap, const int* __restrict__ row_st,
    const float* __restrict__ We, const float* __restrict__ att,
    const float* __restrict__ bias, ushort* __restrict__ out, int N) {
  int n = blockIdx.x * 4 + (threadIdx.x >> 6);
  int lane = threadIdx.x & 63;
  if (n >= N) return;
  const float4 We4 = ((const float4*)We)[lane];
  const float4 at4 = ((const float4*)att)[lane];
  ushort4 xru = *(const ushort4*)(xr + (size_t)n * 256 + lane * 4);
  float xrx = b2f(xru.x), xry = b2f(xru.y), xrz = b2f(xru.z), xrw = b2f(xru.w);
  int a = row_st[n], b = row_st[n + 1];
  float m = -INFINITY, den = 0.f;
  float ax = 0.f, ay = 0.f, az = 0.f, aw = 0.f;
  int sn_nx = srcp[a];
  float av_nx = eap[a];
  for (int i = a; i < b; ++i) {
    int sn = sn_nx;
    float av = av_nx;
    ushort4 xu = *(const ushort4*)(xl + (size_t)sn * 256 + lane * 4);
    if (i + 1 < b) { sn_nx = srcp[i + 1]; av_nx = eap[i + 1]; }
    float x0 = b2f(xu.x), x1 = b2f(xu.y), x2 = b2f(xu.z), x3 = b2f(xu.w);
    float vx = x0 + xrx + av * We4.x; vx = vx > 0.f ? vx : 0.2f * vx;
    float vy = x1 + xry + av * We4.y; vy = vy > 0.f ? vy : 0.2f * vy;
    float vz = x2 + xrz + av * We4.z; vz = vz > 0.f ? vz : 0.2f * vz;
    float vw = x3 + xrw + av * We4.w; vw = vw > 0.f ? vw : 0.2f * vw;
    float t = at4.x * vx + at4.y * vy + at4.z * vz + at4.w * vw;
    t += __shfl_xor(t, 1, 16);
    t += __shfl_xor(t, 2, 16);
    t += __shfl_xor(t, 4, 16);
    t += __shfl_xor(t, 8, 16);
    if (t > m) {
      float sc = __expf(m - t);
      m = t;
      den *= sc; ax *= sc; ay *= sc; az *= sc; aw *= sc;
    }
    float ex = __expf(t - m);
    den += ex;
    ax += ex * x0; ay += ex * x1; az += ex * x2; aw += ex * x3;
  }
  float inv = 1.f / (den + 1e-16f);
  const float4 b4 = ((const float4*)bias)[lane];
  ushort4 o;
  o.x = f2b(fmaxf(ax * inv + b4.x, 0.f));
  o.y = f2b(fmaxf(ay * inv + b4.y, 0.f));
  o.z = f2b(fmaxf(az * inv + b4.z, 0.f));
  o.w = f2b(fmaxf(aw * inv + b4.w, 0.f));
  *(ushort4*)(out + (size_t)n * 256 + lane * 4) = o;
}

// ---------------- layer 2 fused (H=1, C=64) ----------------
__global__ __launch_bounds__(256) void k_fused2(const ushort* __restrict__ xl,
    const ushort* __restrict__ xr, const int* __restrict__ srcp,
    const float* __restrict__ eap, const int* __restrict__ row_st,
    const float* __restrict__ We, const float* __restrict__ att,
    const float* __restrict__ bias, float* __restrict__ out, int N) {
  int n = blockIdx.x * 4 + (threadIdx.x >> 6);
  int lane = threadIdx.x & 63;
  if (n >= N) return;
  const float Wev = We[lane];
  const float atv = att[lane];
  const float xrv = b2f(xr[(size_t)n * 64 + lane]);
  int a = row_st[n], b = row_st[n + 1];
  float m = -INFINITY, den = 0.f, acc = 0.f;
  int sn_nx = srcp[a];
  float av_nx = eap[a];
  for (int i = a; i < b; ++i) {
    int sn = sn_nx;
    float av = av_nx;
    float xv = b2f(xl[(size_t)sn * 64 + lane]);
    if (i + 1 < b) { sn_nx = srcp[i + 1]; av_nx = eap[i + 1]; }
    float v = xv + xrv + av * Wev;
    v = v > 0.f ? v : 0.2f * v;
    float t = wred_sum(atv * v);
    if (t > m) {
      float sc = __expf(m - t);
      m = t; den *= sc; acc *= sc;
    }
    float ex = __expf(t - m);
    den += ex;
    acc += ex * xv;
  }
  float v = acc / (den + 1e-16f) + bias[lane];
  out[(size_t)n * 64 + lane] = v > 0.f ? v : 0.f;
}

// ---------------- global mean pool ----------------
__global__ __launch_bounds__(256) void k_pool(const float* __restrict__ h2,
    float* __restrict__ g_sum, int N) {
  __shared__ float red[4][64];
  int b = blockIdx.x, tid = threadIdx.x;
  int lane = tid & 63, w = tid >> 6;
  int rows_per = (N + gridDim.x - 1) / gridDim.x;
  int r0 = b * rows_per, r1 = min(r0 + rows_per, N);
  float s = 0;
  for (int r = r0 + w; r < r1; r += 4) s += h2[(size_t)r * 64 + lane];
  red[w][lane] = s;
  __syncthreads();
  if (w == 0) {
    float v = red[0][lane] + red[1][lane] + red[2][lane] + red[3][lane];
    atomicAdd(&g_sum[lane], v);
  }
}

// mean -> g, state potential, sigmoid(alpha)
__global__ void k_head(const float* __restrict__ g_sum, const float* __restrict__ Wp,
    const float* __restrict__ bp, const float* __restrict__ alpha,
    float* __restrict__ g, float* __restrict__ out, int N, int NA) {
  int lane = threadIdx.x;
  float gv = g_sum[lane] / (float)N;
  g[lane] = gv;
  float t = wred_sum(gv * Wp[lane]);
  if (lane == 0) {
    float sp = t + bp[0];
    out[NA] = sp > 0.f ? sp : 0.f;
    out[NA + 1] = 1.f / (1.f + __expf(-alpha[0]));
  }
}

__global__ void k_aflag(const int* __restrict__ actions, unsigned char* __restrict__ aflag,
                        int n_act) {
  int i = threadIdx.x;
  if (i < n_act) aflag[actions[i]] = 1;
}

// ---------------- masked logits: coalesced GEMV, grid-stride, 1 atomic/block ----------------
__global__ __launch_bounds__(256) void k_logits(const float* __restrict__ g,
    const float* __restrict__ Wf, const float* __restrict__ bf,
    const unsigned char* __restrict__ aflag, const int* __restrict__ src,
    const int* __restrict__ dst, float* __restrict__ logits,
    unsigned* __restrict__ gmax_key, int E, int NA) {
  __shared__ float gs[64];
  __shared__ float wmax[4];
  int tid = threadIdx.x;
  if (tid < 64) gs[tid] = g[tid];
  __syncthreads();
  int l16 = tid & 15;
  float4 gv = ((const float4*)gs)[l16];
  float gmaxl = -INFINITY;
  for (int row = blockIdx.x * 16 + (tid >> 4); row < NA; row += gridDim.x * 16) {
    float val = -INFINITY;
    bool keep = (!aflag[row]) && (row >= E || src[row] != dst[row]);
    if (keep) {
      float4 w = *(const float4*)(Wf + (size_t)row * 64 + l16 * 4);
      float acc = w.x * gv.x + w.y * gv.y + w.z * gv.z + w.w * gv.w;
      acc += __shfl_xor(acc, 1, 16);
      acc += __shfl_xor(acc, 2, 16);
      acc += __shfl_xor(acc, 4, 16);
      acc += __shfl_xor(acc, 8, 16);
      val = acc + bf[row];
    }
    if (l16 == 0) logits[row] = val;
    gmaxl = fmaxf(gmaxl, val);
  }
  gmaxl = wred_max(gmaxl);
  if ((tid & 63) == 0) wmax[tid >> 6] = gmaxl;
  __syncthreads();
  if (tid == 0) {
    float m = fmaxf(fmaxf(wmax[0], wmax[1]), fmaxf(wmax[2], wmax[3]));
    atomicMax(gmax_key, f2key(m));
  }
}

// ---------------- exp pass: float4, 1 atomic/block ----------------
__global__ __launch_bounds__(256) void k_exp(float* __restrict__ logits,
    const unsigned* __restrict__ gmax_key, float* __restrict__ gsum, int NA) {
  __shared__ float wsum[4];
  int i = (blockIdx.x * 256 + threadIdx.x) * 4;
  float gmax = key2f(*gmax_key);
  float s = 0.f;
  if (i < NA) {
    float4 v = *(const float4*)(logits + i);   // logits buffer padded past NA
    float4 e;
    e.x = (i + 0 < NA && v.x != -INFINITY) ? __expf(v.x - gmax) : 0.f;
    e.y = (i + 1 < NA && v.y != -INFINITY) ? __expf(v.y - gmax) : 0.f;
    e.z = (i + 2 < NA && v.z != -INFINITY) ? __expf(v.z - gmax) : 0.f;
    e.w = (i + 3 < NA && v.w != -INFINITY) ? __expf(v.w - gmax) : 0.f;
    *(float4*)(logits + i) = e;
    s = e.x + e.y + e.z + e.w;
  }
  s = wred_sum(s);
  if ((threadIdx.x & 63) == 0) wsum[threadIdx.x >> 6] = s;
  __syncthreads();
  if (threadIdx.x == 0)
    atomicAdd(gsum, wsum[0] + wsum[1] + wsum[2] + wsum[3]);
}

__global__ __launch_bounds__(256) void k_norm(const float* __restrict__ logits,
    const float* __restrict__ gsum, float* __restrict__ out, int NA) {
  int i = (blockIdx.x * 256 + threadIdx.x) * 4;
  if (i >= NA) return;
  float inv = 1.f / (*gsum);
  if (i + 3 < NA) {
    float4 v = *(const float4*)(logits + i);
    float4 o;
    o.x = v.x * inv; o.y = v.y * inv; o.z = v.z * inv; o.w = v.w * inv;
    *(float4*)(out + i) = o;
  } else {
    for (int j = i; j < NA; ++j) out[j] = logits[j] * inv;
  }
}

// ---------------- launch ----------------
extern "C" void kernel_launch(void* const* d_in, const int* in_sizes, int n_in,
                              void* d_out, int out_size, void* d_ws, size_t ws_size,
                              hipStream_t stream) {
  const float* x      = (const float*)d_in[0];
  const int*   eidx   = (const int*)d_in[1];
  const float* eattr  = (const float*)d_in[2];
  const int*   actions= (const int*)d_in[3];
  const float* Wl1 = (const float*)d_in[4];
  const float* bl1 = (const float*)d_in[5];
  const float* Wr1 = (const float*)d_in[6];
  const float* br1 = (const float*)d_in[7];
  const float* We1 = (const float*)d_in[8];
  const float* att1= (const float*)d_in[9];
  const float* bias1=(const float*)d_in[10];
  const float* Wl2 = (const float*)d_in[11];
  const float* bl2 = (const float*)d_in[12];
  const float* Wr2 = (const float*)d_in[13];
  const float* br2 = (const float*)d_in[14];
  const float* We2 = (const float*)d_in[15];
  const float* att2= (const float*)d_in[16];
  const float* bias2=(const float*)d_in[17];
  const float* Wf  = (const float*)d_in[18];
  const float* bf  = (const float*)d_in[19];
  const float* Wp  = (const float*)d_in[20];
  const float* bp  = (const float*)d_in[21];
  const float* alpha=(const float*)d_in[22];

  const int F = 128;
  const int N = in_sizes[0] / F;       // 20000
  const int E = in_sizes[2];           // 400000
  const int E2 = E + N;
  const int NA = E + 1;
  const int n_act = in_sizes[3];
  const int* src = eidx;
  const int* dst = eidx + E;
  const int hid = 64;

  float* ws = (float*)d_ws;
  size_t p = 0;
  int*      cnt_i    = (int*)(ws + p);      p += (size_t)N;
  float*    sum_ea   = ws + p;              p += (size_t)N;
  float*    g_sum    = ws + p;              p += 64;
  unsigned* gmax_key = (unsigned*)(ws + p); p += 64;
  float*    gsum     = ws + p;              p += 64;
  size_t zero_bytes = p * sizeof(float);
  float*    g        = ws + p;              p += 64;
  float*    mean_ea  = ws + p;              p += (size_t)N;
  int*      row_st   = (int*)(ws + p);      p += (size_t)N + 64;
  int*      cursor   = (int*)(ws + p);      p += (size_t)N;
  int*      srcp     = (int*)(ws + p);      p += (size_t)E2;
  float*    eap      = ws + p;              p += (size_t)E2;
  float*    logits   = ws + p;              p += (size_t)NA + 64;
  p = (p + 3) & ~(size_t)3;                 // 16B align for bf16 region
  float*    h2       = ws + p;              p += (size_t)N * hid;
  ushort* ub = (ushort*)(ws + p);
  size_t q = 0;
  ushort* xb   = ub + q; q += (size_t)N * F;        // x bf16
  ushort* wl1b = ub + q; q += (size_t)256 * 128;
  ushort* wr1b = ub + q; q += (size_t)256 * 128;
  ushort* wl2b = ub + q; q += (size_t)64 * 256;
  ushort* wr2b = ub + q; q += (size_t)64 * 256;
  ushort* xl1b = ub + q; q += (size_t)N * 256;
  ushort* xr1b = ub + q; q += (size_t)N * 256;
  ushort* h1b  = ub + q; q += (size_t)N * 256;
  ushort* xl2b = ub + q; q += (size_t)N * 64;
  ushort* xr2b = ub + q; q += (size_t)N * 64;
  unsigned char* aflag = (unsigned char*)(ub + q);

  float* out = (float*)d_out;

  hipMemsetAsync(d_ws, 0, zero_bytes, stream);
  hipMemsetAsync(aflag, 0, (size_t)NA, stream);

  // casts: x + 4 weight matrices -> bf16
  {
    int n0 = N * F, n1 = 256 * 128, n2 = 256 * 128, n3 = 64 * 256, n4 = 64 * 256;
    int tot4 = (n0 + n1 + n2 + n3 + n4) / 4;
    k_cast5<<<(tot4 + 255) / 256, 256, 0, stream>>>(
        x, xb, n0, Wl1, wl1b, n1, Wr1, wr1b, n2, Wl2, wl2b, n3, Wr2, wr2b, n4);
  }

  // CSR build + self-loop edge attr
  k_count_ea<<<(E + 255) / 256, 256, 0, stream>>>(dst, eattr, cnt_i, sum_ea, E);
  k_mean<<<(N + 255) / 256, 256, 0, stream>>>(cnt_i, sum_ea, mean_ea, N);
  k_scan<<<1, 1024, 0, stream>>>(cnt_i, row_st, cursor, N);
  k_scatter<<<(E2 + 255) / 256, 256, 0, stream>>>(dst, src, eattr, mean_ea,
                                                  cursor, srcp, eap, E, E2);

  // layer 1 projections (bf16 MFMA): xl1b, xr1b in one launch
  {
    dim3 g1((N + 63) / 64, 256 / 64, 2);
    k_gemm_mfma2<<<g1, 256, 0, stream>>>(xb, wl1b, bl1, xl1b, wr1b, br1, xr1b,
                                         N, 256, 128);
  }
  k_fused1<<<(N + 3) / 4, 256, 0, stream>>>(xl1b, xr1b, srcp, eap, row_st,
                                            We1, att1, bias1, h1b, N);

  // layer 2 projections from h1b: xl2b, xr2b in one launch
  {
    dim3 g2((N + 63) / 64, 1, 2);
    k_gemm_mfma2<<<g2, 256, 0, stream>>>(h1b, wl2b, bl2, xl2b, wr2b, br2, xr2b,
                                         N, 64, 256);
  }
  k_fused2<<<(N + 3) / 4, 256, 0, stream>>>(xl2b, xr2b, srcp, eap, row_st,
                                            We2, att2, bias2, h2, N);

  // head
  k_pool<<<128, 256, 0, stream>>>(h2, g_sum, N);
  k_head<<<1, 64, 0, stream>>>(g_sum, Wp, bp, alpha, g, out, N, NA);
  k_aflag<<<1, 128, 0, stream>>>(actions, aflag, n_act);
  k_logits<<<1024, 256, 0, stream>>>(g, Wf, bf, aflag, src, dst,
                                     logits, gmax_key, E, NA);
  int nb4 = (NA + 1023) / 1024;
  k_exp<<<nb4, 256, 0, stream>>>(logits, gmax_key, gsum, NA);
  k_norm<<<nb4, 256, 0, stream>>>(logits, gsum, out, NA);
}